// Round 2
// baseline (9659.641 us; speedup 1.0000x reference)
//
#include <hip/hip_runtime.h>
#include <hip/hip_bf16.h>

#define N_NODES  50000
#define N_EDGES  800000
#define DIM      64
#define N_GRAPHS 64
#define OUT_DIM  10
#define NBLK_N   196   // ceil(50000/256)

// ---------------- CSR build ----------------

__global__ __launch_bounds__(256) void count_kernel(const int* __restrict__ dst,
                                                    int* __restrict__ cnt) {
    int e = blockIdx.x * 256 + threadIdx.x;
    if (e < N_EDGES) atomicAdd(&cnt[dst[e]], 1);
}

__global__ __launch_bounds__(256) void scan1(const int* __restrict__ cnt,
                                             int* __restrict__ offs,
                                             int* __restrict__ bsums) {
    __shared__ int s[256];
    int t = threadIdx.x;
    int i = blockIdx.x * 256 + t;
    int v = (i < N_NODES) ? cnt[i] : 0;
    s[t] = v;
    __syncthreads();
    for (int d = 1; d < 256; d <<= 1) {
        int tmp = (t >= d) ? s[t - d] : 0;
        __syncthreads();
        s[t] += tmp;
        __syncthreads();
    }
    if (i < N_NODES) offs[i] = s[t] - v;   // exclusive
    if (t == 255) bsums[blockIdx.x] = s[255];
}

__global__ void scan2(int* bsums, int nb) {
    __shared__ int s[256];
    int t = threadIdx.x;
    int v = (t < nb) ? bsums[t] : 0;
    s[t] = v;
    __syncthreads();
    for (int d = 1; d < 256; d <<= 1) {
        int tmp = (t >= d) ? s[t - d] : 0;
        __syncthreads();
        s[t] += tmp;
        __syncthreads();
    }
    if (t < nb) bsums[t] = s[t] - v;       // exclusive
}

__global__ __launch_bounds__(256) void scan3(int* __restrict__ offs,
                                             const int* __restrict__ bsums) {
    int i = blockIdx.x * 256 + threadIdx.x;
    if (i < N_NODES) offs[i] += bsums[blockIdx.x];
    if (i == 0) offs[N_NODES] = N_EDGES;
}

__global__ __launch_bounds__(256) void scatter_kernel(const int* __restrict__ src,
                                                      const int* __restrict__ dst,
                                                      const int* __restrict__ offs,
                                                      int* __restrict__ cur,
                                                      int* __restrict__ csr_src) {
    int e = blockIdx.x * 256 + threadIdx.x;
    if (e < N_EDGES) {
        int d = dst[e];
        int pos = offs[d] + atomicAdd(&cur[d], 1);
        csr_src[pos] = src[e];
    }
}

// ---------------- per-layer fused GEMM: q,k,v,(h@Ws+bs) ----------------
// block = 256 threads = 4 waves; wave w ("chunk") owns one W matrix.
// 64 nodes/block, lane = node. W in LDS [i][chunk*64+j] (64KB), broadcast reads.
__global__ __launch_bounds__(256) void gemm_qkvs(
    const float* __restrict__ h,
    const float* __restrict__ Wq, const float* __restrict__ Wk,
    const float* __restrict__ Wv, const float* __restrict__ Ws,
    const float* __restrict__ bq, const float* __restrict__ bk,
    const float* __restrict__ bv, const float* __restrict__ bs,
    float* __restrict__ q, float* __restrict__ kv, float* __restrict__ hnext) {
    __shared__ float smem[64 * 256];   // 64KB
    int t = threadIdx.x;
    int nb = blockIdx.x * 64;
    int lane = t & 63, chunk = t >> 6;

    const float* Wm  = (chunk == 0) ? Wq : (chunk == 1) ? Wk : (chunk == 2) ? Wv : Ws;
    const float* bm  = (chunk == 0) ? bq : (chunk == 1) ? bk : (chunk == 2) ? bv : bs;

    // vectorized cooperative W load: 16 float4 per thread, coalesced
    #pragma unroll
    for (int it = 0; it < 16; ++it) {
        int elem = it * 256 + lane * 4;
        int i = elem >> 6, j = elem & 63;
        float4 w = *(const float4*)(Wm + elem);
        *(float4*)(smem + i * 256 + chunk * 64 + j) = w;
    }

    // own h row -> registers
    int n = nb + lane;
    float4 hreg[16];
    const float4* hp = (const float4*)(h + (size_t)(n < N_NODES ? n : 0) * DIM);
    #pragma unroll
    for (int i4 = 0; i4 < 16; ++i4) hreg[i4] = hp[i4];

    float acc[64];
    #pragma unroll
    for (int j = 0; j < 64; ++j) acc[j] = bm[j];

    __syncthreads();

    const float* wbase = smem + chunk * 64;
    const float* hr = (const float*)hreg;
    #pragma unroll
    for (int i = 0; i < 64; ++i) {
        float hv = hr[i];
        const float4* wr = (const float4*)(wbase + i * 256);
        #pragma unroll
        for (int j4 = 0; j4 < 16; ++j4) {
            float4 w = wr[j4];
            acc[j4 * 4 + 0] += hv * w.x;
            acc[j4 * 4 + 1] += hv * w.y;
            acc[j4 * 4 + 2] += hv * w.z;
            acc[j4 * 4 + 3] += hv * w.w;
        }
    }

    // direct vectorized stores (no staging, no extra syncs)
    if (n < N_NODES) {
        float* outp = (chunk == 0) ? q + (size_t)n * 64
                    : (chunk == 1) ? kv + (size_t)n * 128
                    : (chunk == 2) ? kv + (size_t)n * 128 + 64
                                   : hnext + (size_t)n * 64;
        #pragma unroll
        for (int j4 = 0; j4 < 16; ++j4) {
            *(float4*)(outp + j4 * 4) =
                make_float4(acc[j4 * 4], acc[j4 * 4 + 1], acc[j4 * 4 + 2], acc[j4 * 4 + 3]);
        }
    }
}

// ---------------- edge attention ----------------
// one wave per dst node; 4 groups of 16 lanes, group g owns edge e+g,
// lane holds dims [4*lg, 4*lg+4). Online softmax with per-group partials.
__global__ __launch_bounds__(256) void edge_attn(
    const float* __restrict__ q, const float* __restrict__ kv,
    const int* __restrict__ offs, const int* __restrict__ csr_src,
    float* __restrict__ hnext) {
    int wave = threadIdx.x >> 6, lane = threadIdx.x & 63;
    int n = blockIdx.x * 4 + wave;
    if (n >= N_NODES) return;
    int g  = lane >> 4;
    int lg = lane & 15;
    float4 qv = *(const float4*)(q + (size_t)n * 64 + lg * 4);
    int e0 = offs[n], e1 = offs[n + 1];
    float m = -3.0e38f, z = 0.f;
    float4 acc = make_float4(0.f, 0.f, 0.f, 0.f);
    for (int e = e0; e < e1; e += 4) {
        int eg = e + g;
        bool valid = (eg < e1);
        int sg = valid ? csr_src[eg] : 0;
        const float* kvp = kv + (size_t)sg * 128 + lg * 4;
        float4 k4 = valid ? *(const float4*)kvp : make_float4(0.f, 0.f, 0.f, 0.f);
        float4 v4 = valid ? *(const float4*)(kvp + 64) : make_float4(0.f, 0.f, 0.f, 0.f);
        float d = qv.x * k4.x + qv.y * k4.y + qv.z * k4.z + qv.w * k4.w;
        d += __shfl_xor(d, 1);
        d += __shfl_xor(d, 2);
        d += __shfl_xor(d, 4);
        d += __shfl_xor(d, 8);
        float a = valid ? d * 0.125f : -3.0e38f;   // 1/sqrt(64)
        float t2 = fmaxf(m, a);
        t2 = fmaxf(t2, __shfl_xor(t2, 16));
        t2 = fmaxf(t2, __shfl_xor(t2, 32));       // wave-common new max
        float c = __expf(m - t2);
        float p = __expf(a - t2);                 // 0 for invalid slots
        m = t2;
        z = z * c + p;
        acc.x = acc.x * c + p * v4.x;
        acc.y = acc.y * c + p * v4.y;
        acc.z = acc.z * c + p * v4.z;
        acc.w = acc.w * c + p * v4.w;
    }
    // cross-group reduction (groups hold partial z/acc for their edge subsets)
    z += __shfl_xor(z, 16); z += __shfl_xor(z, 32);
    acc.x += __shfl_xor(acc.x, 16); acc.x += __shfl_xor(acc.x, 32);
    acc.y += __shfl_xor(acc.y, 16); acc.y += __shfl_xor(acc.y, 32);
    acc.z += __shfl_xor(acc.z, 16); acc.z += __shfl_xor(acc.z, 32);
    acc.w += __shfl_xor(acc.w, 16); acc.w += __shfl_xor(acc.w, 32);
    float invz = 1.f / (z + 1e-16f);
    if (g == 0) {
        float* hp = hnext + (size_t)n * 64 + lg * 4;
        float4 h4 = *(const float4*)hp;
        h4.x += acc.x * invz;
        h4.y += acc.y * invz;
        h4.z += acc.z * invz;
        h4.w += acc.w * invz;
        *(float4*)hp = h4;
    }
}

// ---------------- pool + final linear ----------------
__device__ __forceinline__ int lbound(const int* a, int n, int key) {
    int lo = 0, hi = n;
    while (lo < hi) {
        int mid = (lo + hi) >> 1;
        if (a[mid] < key) lo = mid + 1; else hi = mid;
    }
    return lo;
}

__global__ __launch_bounds__(256) void pool_out(const float* __restrict__ h,
                                                const int* __restrict__ batch,
                                                const float* __restrict__ Wf,
                                                const float* __restrict__ bf,
                                                float* __restrict__ out) {
    __shared__ float ps[4][64];
    __shared__ float pl[64];
    int g = blockIdx.x, t = threadIdx.x;
    int lo = lbound(batch, N_NODES, g);
    int hi = lbound(batch, N_NODES, g + 1);
    int cnt = hi - lo;
    int sub = t >> 6, d = t & 63;
    float a = 0.f;
    for (int n2 = lo + sub; n2 < hi; n2 += 4) a += h[(size_t)n2 * 64 + d];
    ps[sub][d] = a;
    __syncthreads();
    if (t < 64) {
        float s = ps[0][t] + ps[1][t] + ps[2][t] + ps[3][t];
        pl[t] = s / (float)(cnt > 1 ? cnt : 1);
    }
    __syncthreads();
    if (t < OUT_DIM) {
        float o = bf[t];
        for (int d2 = 0; d2 < 64; ++d2) o += pl[d2] * Wf[d2 * OUT_DIM + t];
        out[g * OUT_DIM + t] = o;
    }
}

// ---------------- launch ----------------
extern "C" void kernel_launch(void* const* d_in, const int* in_sizes, int n_in,
                              void* d_out, int out_size, void* d_ws, size_t ws_size,
                              hipStream_t stream) {
    const float* x    = (const float*)d_in[0];
    const int*   ei   = (const int*)d_in[1];
    const int*   batch= (const int*)d_in[2];
    const float* Wq   = (const float*)d_in[3];
    const float* bq   = (const float*)d_in[4];
    const float* Wk   = (const float*)d_in[5];
    const float* bk   = (const float*)d_in[6];
    const float* Wv   = (const float*)d_in[7];
    const float* bv   = (const float*)d_in[8];
    const float* Ws   = (const float*)d_in[9];
    const float* bs   = (const float*)d_in[10];
    const float* Wf   = (const float*)d_in[11];
    const float* bf   = (const float*)d_in[12];
    float* out = (float*)d_out;

    char* ws = (char*)d_ws;
    float* qb   = (float*)(ws + 0);            // 12.8MB
    float* kvb  = (float*)(ws + 12800000);     // 25.6MB
    float* hA   = (float*)(ws + 38400000);     // 12.8MB
    float* hB   = (float*)(ws + 51200000);     // 12.8MB
    int*   csr  = (int*)  (ws + 64000000);     // 3.2MB
    int*   offs = (int*)  (ws + 67200000);     // 200004 B
    int*   cur  = (int*)  (ws + 67400704);     // 200000 B
    int*   bsums= (int*)  (ws + 67600704);     // ~1KB

    const int* srcI = ei;
    const int* dstI = ei + N_EDGES;

    // CSR build (recomputed every call; deterministic work)
    hipMemsetAsync(cur, 0, N_NODES * sizeof(int), stream);
    count_kernel<<<N_EDGES / 256, 256, 0, stream>>>(dstI, cur);
    scan1<<<NBLK_N, 256, 0, stream>>>(cur, offs, bsums);
    scan2<<<1, 256, 0, stream>>>(bsums, NBLK_N);
    scan3<<<NBLK_N, 256, 0, stream>>>(offs, bsums);
    hipMemsetAsync(cur, 0, N_NODES * sizeof(int), stream);
    scatter_kernel<<<N_EDGES / 256, 256, 0, stream>>>(srcI, dstI, offs, cur, csr);

    const float* hin = x;
    float* hout = hA;
    for (int l = 0; l < 4; ++l) {
        gemm_qkvs<<<(N_NODES + 63) / 64, 256, 0, stream>>>(
            hin, Wq + l * 4096, Wk + l * 4096, Wv + l * 4096, Ws + l * 4096,
            bq + l * 64, bk + l * 64, bv + l * 64, bs + l * 64,
            qb, kvb, hout);
        edge_attn<<<N_NODES / 4, 256, 0, stream>>>(qb, kvb, offs, csr, hout);
        hin = hout;
        hout = (hout == hA) ? hB : hA;
    }
    pool_out<<<N_GRAPHS, 256, 0, stream>>>(hin, batch, Wf, bf, out);
}

// Round 3
// 362.327 us; speedup vs baseline: 26.6600x; 26.6600x over previous
//
#include <hip/hip_runtime.h>
#include <hip/hip_bf16.h>

typedef unsigned short u16;
typedef unsigned int   u32;
typedef short bf16x8 __attribute__((ext_vector_type(8)));
typedef float f32x4  __attribute__((ext_vector_type(4)));

#define N_NODES  50000
#define N_EDGES  800000
#define DIM      64
#define N_GRAPHS 64
#define OUT_DIM  10
#define NBLK_N   196   // ceil(50000/256)

__device__ __forceinline__ u16 f2bf(float f) {
    u32 u = __float_as_uint(f);
    u32 r = (u + 0x7fffu + ((u >> 16) & 1u)) >> 16;
    return (u16)r;
}
__device__ __forceinline__ float bf_lo(u32 u) { return __uint_as_float(u << 16); }
__device__ __forceinline__ float bf_hi(u32 u) { return __uint_as_float(u & 0xffff0000u); }

// ---------------- CSR build ----------------

__global__ __launch_bounds__(256) void count_kernel(const int* __restrict__ dst,
                                                    int* __restrict__ cnt) {
    int e = blockIdx.x * 256 + threadIdx.x;
    if (e < N_EDGES) atomicAdd(&cnt[dst[e]], 1);
}

__global__ __launch_bounds__(256) void scan1(const int* __restrict__ cnt,
                                             int* __restrict__ offs,
                                             int* __restrict__ bsums) {
    __shared__ int s[256];
    int t = threadIdx.x;
    int i = blockIdx.x * 256 + t;
    int v = (i < N_NODES) ? cnt[i] : 0;
    s[t] = v;
    __syncthreads();
    for (int d = 1; d < 256; d <<= 1) {
        int tmp = (t >= d) ? s[t - d] : 0;
        __syncthreads();
        s[t] += tmp;
        __syncthreads();
    }
    if (i < N_NODES) offs[i] = s[t] - v;   // exclusive
    if (t == 255) bsums[blockIdx.x] = s[255];
}

__global__ void scan2(int* bsums, int nb) {
    __shared__ int s[256];
    int t = threadIdx.x;
    int v = (t < nb) ? bsums[t] : 0;
    s[t] = v;
    __syncthreads();
    for (int d = 1; d < 256; d <<= 1) {
        int tmp = (t >= d) ? s[t - d] : 0;
        __syncthreads();
        s[t] += tmp;
        __syncthreads();
    }
    if (t < nb) bsums[t] = s[t] - v;       // exclusive
}

__global__ __launch_bounds__(256) void scan3(int* __restrict__ offs,
                                             const int* __restrict__ bsums) {
    int i = blockIdx.x * 256 + threadIdx.x;
    if (i < N_NODES) offs[i] += bsums[blockIdx.x];
    if (i == 0) offs[N_NODES] = N_EDGES;
}

__global__ __launch_bounds__(256) void scatter_kernel(const int* __restrict__ src,
                                                      const int* __restrict__ dst,
                                                      const int* __restrict__ offs,
                                                      int* __restrict__ cur,
                                                      int* __restrict__ csr_src) {
    int e = blockIdx.x * 256 + threadIdx.x;
    if (e < N_EDGES) {
        int d = dst[e];
        int pos = offs[d] + atomicAdd(&cur[d], 1);
        csr_src[pos] = src[e];
    }
}

// ---------------- precompute: x -> bf16, W -> bf16 transposed ----------------

__global__ __launch_bounds__(256) void convert_x(const float* __restrict__ x,
                                                 u16* __restrict__ hb) {
    int c = blockIdx.x * 256 + threadIdx.x;      // chunk of 8 elems
    if (c >= N_NODES * 8) return;
    const float* src = x + (size_t)c * 8;
    float4 f0 = *(const float4*)src;
    float4 f1 = *(const float4*)(src + 4);
    uint4 pk;
    pk.x = (u32)f2bf(f0.x) | ((u32)f2bf(f0.y) << 16);
    pk.y = (u32)f2bf(f0.z) | ((u32)f2bf(f0.w) << 16);
    pk.z = (u32)f2bf(f1.x) | ((u32)f2bf(f1.y) << 16);
    pk.w = (u32)f2bf(f1.z) | ((u32)f2bf(f1.w) << 16);
    *(uint4*)(hb + (size_t)c * 8) = pk;
}

// Wtb[l][m*64+col][k]  (bf16), from W[l][k][col] fp32
__global__ __launch_bounds__(256) void transpose_w(
    const float* __restrict__ Wq, const float* __restrict__ Wk,
    const float* __restrict__ Wv, const float* __restrict__ Ws,
    u16* __restrict__ Wtb) {
    int id = blockIdx.x * 256 + threadIdx.x;     // 8192 total
    if (id >= 8192) return;
    int kc  = id & 7;
    int col = (id >> 3) & 63;
    int m   = (id >> 9) & 3;
    int l   = id >> 11;
    const float* W = ((m == 0) ? Wq : (m == 1) ? Wk : (m == 2) ? Wv : Ws) + l * 4096;
    u16 b[8];
    #pragma unroll
    for (int j = 0; j < 8; ++j) b[j] = f2bf(W[(kc * 8 + j) * 64 + col]);
    uint4 pk;
    pk.x = (u32)b[0] | ((u32)b[1] << 16);
    pk.y = (u32)b[2] | ((u32)b[3] << 16);
    pk.z = (u32)b[4] | ((u32)b[5] << 16);
    pk.w = (u32)b[6] | ((u32)b[7] << 16);
    *(uint4*)(Wtb + ((size_t)(l * 256 + m * 64 + col)) * 64 + kc * 8) = pk;
}

// ---------------- fused MFMA GEMM: q (f32), k|v (bf16), h@Ws+bs (f32) ----------------
// block = 256 thr = 4 waves; 64 nodes/block; wave w computes matrix w (64 cols).
// A = h[64 nodes][64 k] bf16, B = Wt[256 cols][64 k] bf16, rows padded to 72.
__global__ __launch_bounds__(256) void gemm_mfma(
    const u16* __restrict__ hb, const u16* __restrict__ Wtb,
    const float* __restrict__ bq, const float* __restrict__ bk,
    const float* __restrict__ bv, const float* __restrict__ bs,
    float* __restrict__ q, u16* __restrict__ kv, float* __restrict__ hnext) {
    __shared__ u16 Alds[64 * 72];    //  9216 B
    __shared__ u16 Blds[256 * 72];   // 36864 B
    int t = threadIdx.x;
    int wave = t >> 6, lane = t & 63;
    int nb = blockIdx.x * 64;

    // stage A (512 16B-chunks) and B (2048 16B-chunks), padded rows
    #pragma unroll
    for (int i = 0; i < 2; ++i) {
        int c = t + 256 * i;
        int row = c >> 3, k8 = c & 7;
        int node = nb + row;
        if (node >= N_NODES) node = 0;
        *(uint4*)(Alds + row * 72 + k8 * 8) =
            *(const uint4*)(hb + (size_t)node * 64 + k8 * 8);
    }
    #pragma unroll
    for (int i = 0; i < 8; ++i) {
        int c = t + 256 * i;
        int col = c >> 3, k8 = c & 7;
        *(uint4*)(Blds + col * 72 + k8 * 8) =
            *(const uint4*)(Wtb + (size_t)col * 64 + k8 * 8);
    }
    __syncthreads();

    int lr = lane & 15, lg4 = lane >> 4;
    const float* bm = (wave == 0) ? bq : (wave == 1) ? bk : (wave == 2) ? bv : bs;

    f32x4 acc[4][4];
    #pragma unroll
    for (int ct = 0; ct < 4; ++ct) {
        float bval = bm[ct * 16 + lr];
        #pragma unroll
        for (int rt = 0; rt < 4; ++rt) acc[rt][ct] = (f32x4){bval, bval, bval, bval};
    }

    #pragma unroll
    for (int s = 0; s < 2; ++s) {
        bf16x8 af[4], bfr[4];
        #pragma unroll
        for (int rt = 0; rt < 4; ++rt)
            af[rt] = *(const bf16x8*)(Alds + (rt * 16 + lr) * 72 + s * 32 + lg4 * 8);
        #pragma unroll
        for (int ct = 0; ct < 4; ++ct)
            bfr[ct] = *(const bf16x8*)(Blds + (wave * 64 + ct * 16 + lr) * 72 + s * 32 + lg4 * 8);
        #pragma unroll
        for (int rt = 0; rt < 4; ++rt)
            #pragma unroll
            for (int ct = 0; ct < 4; ++ct)
                acc[rt][ct] = __builtin_amdgcn_mfma_f32_16x16x32_bf16(
                    af[rt], bfr[ct], acc[rt][ct], 0, 0, 0);
    }

    // epilogue: D layout col=lane&15, row=(lane>>4)*4+reg (m89-verified)
    #pragma unroll
    for (int rt = 0; rt < 4; ++rt) {
        #pragma unroll
        for (int r = 0; r < 4; ++r) {
            int row = rt * 16 + lg4 * 4 + r;
            int node = nb + row;
            if (node >= N_NODES) continue;
            if (wave == 0) {
                #pragma unroll
                for (int ct = 0; ct < 4; ++ct)
                    q[(size_t)node * 64 + ct * 16 + lr] = acc[rt][ct][r];
            } else if (wave == 1) {
                #pragma unroll
                for (int ct = 0; ct < 4; ++ct)
                    kv[(size_t)node * 128 + ct * 16 + lr] = f2bf(acc[rt][ct][r]);
            } else if (wave == 2) {
                #pragma unroll
                for (int ct = 0; ct < 4; ++ct)
                    kv[(size_t)node * 128 + 64 + ct * 16 + lr] = f2bf(acc[rt][ct][r]);
            } else {
                #pragma unroll
                for (int ct = 0; ct < 4; ++ct)
                    hnext[(size_t)node * 64 + ct * 16 + lr] = acc[rt][ct][r];
            }
        }
    }
}

// ---------------- edge attention ----------------
// wave per dst node; 8 groups x 8 lanes; group g owns edges e0+g, e0+g+8, ...
// lane holds dims [8*lg, 8*lg+8). Per-group online softmax, one combine at end.
// Also emits bf16 h for next layer's GEMM.
__global__ __launch_bounds__(256) void edge_attn(
    const float* __restrict__ q, const u16* __restrict__ kv,
    const int* __restrict__ offs, const int* __restrict__ csr_src,
    float* __restrict__ hnext, u16* __restrict__ hb) {
    int wave = threadIdx.x >> 6, lane = threadIdx.x & 63;
    int n = blockIdx.x * 4 + wave;
    int g = lane >> 3, lg = lane & 7;
    const float* qp = q + (size_t)n * 64 + lg * 8;
    float4 q0 = *(const float4*)qp;
    float4 q1 = *(const float4*)(qp + 4);
    int e0 = offs[n], e1 = offs[n + 1];
    float m = -3.0e38f, z = 0.f;
    float a8[8] = {0.f, 0.f, 0.f, 0.f, 0.f, 0.f, 0.f, 0.f};
    for (int e = e0 + g; e < e1; e += 8) {
        int sg = csr_src[e];
        const u16* kvp = kv + (size_t)sg * 128 + lg * 8;
        uint4 ku = *(const uint4*)kvp;
        uint4 vu = *(const uint4*)(kvp + 64);
        float d;
        d = bf_lo(ku.x) * q0.x;
        d = fmaf(bf_hi(ku.x), q0.y, d);
        d = fmaf(bf_lo(ku.y), q0.z, d);
        d = fmaf(bf_hi(ku.y), q0.w, d);
        d = fmaf(bf_lo(ku.z), q1.x, d);
        d = fmaf(bf_hi(ku.z), q1.y, d);
        d = fmaf(bf_lo(ku.w), q1.z, d);
        d = fmaf(bf_hi(ku.w), q1.w, d);
        d += __shfl_xor(d, 1);
        d += __shfl_xor(d, 2);
        d += __shfl_xor(d, 4);
        float alpha = d * 0.125f;             // 1/sqrt(64)
        float mn = fmaxf(m, alpha);
        float c = __expf(m - mn);
        float p = __expf(alpha - mn);
        z = z * c + p;
        a8[0] = a8[0] * c + p * bf_lo(vu.x);
        a8[1] = a8[1] * c + p * bf_hi(vu.x);
        a8[2] = a8[2] * c + p * bf_lo(vu.y);
        a8[3] = a8[3] * c + p * bf_hi(vu.y);
        a8[4] = a8[4] * c + p * bf_lo(vu.z);
        a8[5] = a8[5] * c + p * bf_hi(vu.z);
        a8[6] = a8[6] * c + p * bf_lo(vu.w);
        a8[7] = a8[7] * c + p * bf_hi(vu.w);
        m = mn;
    }
    // combine the 8 groups
    float M = m;
    M = fmaxf(M, __shfl_xor(M, 8));
    M = fmaxf(M, __shfl_xor(M, 16));
    M = fmaxf(M, __shfl_xor(M, 32));
    float s = __expf(m - M);
    z *= s;
    z += __shfl_xor(z, 8); z += __shfl_xor(z, 16); z += __shfl_xor(z, 32);
    #pragma unroll
    for (int j = 0; j < 8; ++j) {
        float a = a8[j] * s;
        a += __shfl_xor(a, 8); a += __shfl_xor(a, 16); a += __shfl_xor(a, 32);
        a8[j] = a;
    }
    if (g == 0) {
        float invz = 1.f / (z + 1e-16f);
        float* hp = hnext + (size_t)n * 64 + lg * 8;
        float4 h0 = *(const float4*)hp;
        float4 h1 = *(const float4*)(hp + 4);
        float r0 = h0.x + a8[0] * invz;
        float r1 = h0.y + a8[1] * invz;
        float r2 = h0.z + a8[2] * invz;
        float r3 = h0.w + a8[3] * invz;
        float r4 = h1.x + a8[4] * invz;
        float r5 = h1.y + a8[5] * invz;
        float r6 = h1.z + a8[6] * invz;
        float r7 = h1.w + a8[7] * invz;
        *(float4*)hp = make_float4(r0, r1, r2, r3);
        *(float4*)(hp + 4) = make_float4(r4, r5, r6, r7);
        uint4 pk;
        pk.x = (u32)f2bf(r0) | ((u32)f2bf(r1) << 16);
        pk.y = (u32)f2bf(r2) | ((u32)f2bf(r3) << 16);
        pk.z = (u32)f2bf(r4) | ((u32)f2bf(r5) << 16);
        pk.w = (u32)f2bf(r6) | ((u32)f2bf(r7) << 16);
        *(uint4*)(hb + (size_t)n * 64 + lg * 8) = pk;
    }
}

// ---------------- pool + final linear ----------------
__device__ __forceinline__ int lbound(const int* a, int n, int key) {
    int lo = 0, hi = n;
    while (lo < hi) {
        int mid = (lo + hi) >> 1;
        if (a[mid] < key) lo = mid + 1; else hi = mid;
    }
    return lo;
}

__global__ __launch_bounds__(256) void pool_out(const float* __restrict__ h,
                                                const int* __restrict__ batch,
                                                const float* __restrict__ Wf,
                                                const float* __restrict__ bf,
                                                float* __restrict__ out) {
    __shared__ float ps[4][64];
    __shared__ float pl[64];
    int g = blockIdx.x, t = threadIdx.x;
    int lo = lbound(batch, N_NODES, g);
    int hi = lbound(batch, N_NODES, g + 1);
    int cnt = hi - lo;
    int sub = t >> 6, d = t & 63;
    float a = 0.f;
    for (int n2 = lo + sub; n2 < hi; n2 += 4) a += h[(size_t)n2 * 64 + d];
    ps[sub][d] = a;
    __syncthreads();
    if (t < 64) {
        float s = ps[0][t] + ps[1][t] + ps[2][t] + ps[3][t];
        pl[t] = s / (float)(cnt > 1 ? cnt : 1);
    }
    __syncthreads();
    if (t < OUT_DIM) {
        float o = bf[t];
        for (int d2 = 0; d2 < 64; ++d2) o += pl[d2] * Wf[d2 * OUT_DIM + t];
        out[g * OUT_DIM + t] = o;
    }
}

// ---------------- launch ----------------
extern "C" void kernel_launch(void* const* d_in, const int* in_sizes, int n_in,
                              void* d_out, int out_size, void* d_ws, size_t ws_size,
                              hipStream_t stream) {
    const float* x    = (const float*)d_in[0];
    const int*   ei   = (const int*)d_in[1];
    const int*   batch= (const int*)d_in[2];
    const float* Wq   = (const float*)d_in[3];
    const float* bq   = (const float*)d_in[4];
    const float* Wk   = (const float*)d_in[5];
    const float* bk   = (const float*)d_in[6];
    const float* Wv   = (const float*)d_in[7];
    const float* bv   = (const float*)d_in[8];
    const float* Ws   = (const float*)d_in[9];
    const float* bs   = (const float*)d_in[10];
    const float* Wf   = (const float*)d_in[11];
    const float* bf   = (const float*)d_in[12];
    float* out = (float*)d_out;

    char* ws = (char*)d_ws;
    float* qb   = (float*)(ws + 0);            // 12.8 MB
    float* hA   = (float*)(ws + 12800000);     // 12.8 MB
    float* hB   = (float*)(ws + 25600000);     // 12.8 MB
    u16*   kvb  = (u16*)  (ws + 38400000);     // 12.8 MB (bf16)
    u16*   hb   = (u16*)  (ws + 51200000);     //  6.4 MB (bf16)
    u16*   Wtb  = (u16*)  (ws + 57600000);     //  256 KB
    int*   csr  = (int*)  (ws + 57862144);     //  3.2 MB
    int*   offs = (int*)  (ws + 61062144);     //  200 KB
    int*   cur  = (int*)  (ws + 61262848);     //  200 KB
    int*   bsums= (int*)  (ws + 61463552);     //  ~1 KB

    const int* srcI = ei;
    const int* dstI = ei + N_EDGES;

    // CSR build
    hipMemsetAsync(cur, 0, N_NODES * sizeof(int), stream);
    count_kernel<<<N_EDGES / 256, 256, 0, stream>>>(dstI, cur);
    scan1<<<NBLK_N, 256, 0, stream>>>(cur, offs, bsums);
    scan2<<<1, 256, 0, stream>>>(bsums, NBLK_N);
    scan3<<<NBLK_N, 256, 0, stream>>>(offs, bsums);
    hipMemsetAsync(cur, 0, N_NODES * sizeof(int), stream);
    scatter_kernel<<<N_EDGES / 256, 256, 0, stream>>>(srcI, dstI, offs, cur, csr);

    // bf16 precompute
    convert_x<<<(N_NODES * 8 + 255) / 256, 256, 0, stream>>>(x, hb);
    transpose_w<<<32, 256, 0, stream>>>(Wq, Wk, Wv, Ws, Wtb);

    float* hout = hA;
    const float* hin = nullptr;
    for (int l = 0; l < 4; ++l) {
        gemm_mfma<<<(N_NODES + 63) / 64, 256, 0, stream>>>(
            hb, Wtb + (size_t)l * 16384,
            bq + l * 64, bk + l * 64, bv + l * 64, bs + l * 64,
            qb, kvb, hout);
        edge_attn<<<N_NODES / 4, 256, 0, stream>>>(qb, kvb, offs, csr, hout, hb);
        hin = hout;
        hout = (hout == hA) ? hB : hA;
    }
    pool_out<<<N_GRAPHS, 256, 0, stream>>>(hin, batch, Wf, bf, out);
}

// Round 4
// 335.251 us; speedup vs baseline: 28.8132x; 1.0808x over previous
//
#include <hip/hip_runtime.h>
#include <hip/hip_bf16.h>

typedef unsigned short u16;
typedef unsigned int   u32;
typedef short bf16x8 __attribute__((ext_vector_type(8)));
typedef float f32x4  __attribute__((ext_vector_type(4)));

#define N_NODES  50000
#define N_EDGES  800000
#define DIM      64
#define N_GRAPHS 64
#define OUT_DIM  10
#define NBLK_N   196   // ceil(50000/256)
#define POOL_BLOCKS 256
#define POOL_CHUNK  ((N_NODES + POOL_BLOCKS - 1) / POOL_BLOCKS)   // 196

__device__ __forceinline__ u16 f2bf(float f) {
    u32 u = __float_as_uint(f);
    u32 r = (u + 0x7fffu + ((u >> 16) & 1u)) >> 16;
    return (u16)r;
}
__device__ __forceinline__ float bf_lo(u32 u) { return __uint_as_float(u << 16); }
__device__ __forceinline__ float bf_hi(u32 u) { return __uint_as_float(u & 0xffff0000u); }

// ---------------- CSR build ----------------

__global__ __launch_bounds__(256) void count_kernel(const int* __restrict__ dst,
                                                    int* __restrict__ cnt) {
    int e = blockIdx.x * 256 + threadIdx.x;
    if (e < N_EDGES) atomicAdd(&cnt[dst[e]], 1);
}

__global__ __launch_bounds__(256) void scan1(const int* __restrict__ cnt,
                                             int* __restrict__ offs,
                                             int* __restrict__ bsums) {
    __shared__ int s[256];
    int t = threadIdx.x;
    int i = blockIdx.x * 256 + t;
    int v = (i < N_NODES) ? cnt[i] : 0;
    s[t] = v;
    __syncthreads();
    for (int d = 1; d < 256; d <<= 1) {
        int tmp = (t >= d) ? s[t - d] : 0;
        __syncthreads();
        s[t] += tmp;
        __syncthreads();
    }
    if (i < N_NODES) offs[i] = s[t] - v;   // exclusive
    if (t == 255) bsums[blockIdx.x] = s[255];
}

__global__ void scan2(int* bsums, int nb) {
    __shared__ int s[256];
    int t = threadIdx.x;
    int v = (t < nb) ? bsums[t] : 0;
    s[t] = v;
    __syncthreads();
    for (int d = 1; d < 256; d <<= 1) {
        int tmp = (t >= d) ? s[t - d] : 0;
        __syncthreads();
        s[t] += tmp;
        __syncthreads();
    }
    if (t < nb) bsums[t] = s[t] - v;       // exclusive
}

__global__ __launch_bounds__(256) void scan3(int* __restrict__ offs,
                                             const int* __restrict__ bsums) {
    int i = blockIdx.x * 256 + threadIdx.x;
    if (i < N_NODES) offs[i] += bsums[blockIdx.x];
    if (i == 0) offs[N_NODES] = N_EDGES;
}

__global__ __launch_bounds__(256) void scatter_kernel(const int* __restrict__ src,
                                                      const int* __restrict__ dst,
                                                      const int* __restrict__ offs,
                                                      int* __restrict__ cur,
                                                      int* __restrict__ csr_src) {
    int e = blockIdx.x * 256 + threadIdx.x;
    if (e < N_EDGES) {
        int d = dst[e];
        int pos = offs[d] + atomicAdd(&cur[d], 1);
        csr_src[pos] = src[e];
    }
}

// ---------------- precompute: x -> bf16, W -> bf16 transposed ----------------

__global__ __launch_bounds__(256) void convert_x(const float* __restrict__ x,
                                                 u16* __restrict__ hb) {
    int c = blockIdx.x * 256 + threadIdx.x;      // chunk of 8 elems
    if (c >= N_NODES * 8) return;
    const float* src = x + (size_t)c * 8;
    float4 f0 = *(const float4*)src;
    float4 f1 = *(const float4*)(src + 4);
    uint4 pk;
    pk.x = (u32)f2bf(f0.x) | ((u32)f2bf(f0.y) << 16);
    pk.y = (u32)f2bf(f0.z) | ((u32)f2bf(f0.w) << 16);
    pk.z = (u32)f2bf(f1.x) | ((u32)f2bf(f1.y) << 16);
    pk.w = (u32)f2bf(f1.z) | ((u32)f2bf(f1.w) << 16);
    *(uint4*)(hb + (size_t)c * 8) = pk;
}

// Wtb[l][m*64+col][k]  (bf16), from W[l][k][col] fp32
__global__ __launch_bounds__(256) void transpose_w(
    const float* __restrict__ Wq, const float* __restrict__ Wk,
    const float* __restrict__ Wv, const float* __restrict__ Ws,
    u16* __restrict__ Wtb) {
    int id = blockIdx.x * 256 + threadIdx.x;     // 8192 total
    if (id >= 8192) return;
    int kc  = id & 7;
    int col = (id >> 3) & 63;
    int m   = (id >> 9) & 3;
    int l   = id >> 11;
    const float* W = ((m == 0) ? Wq : (m == 1) ? Wk : (m == 2) ? Wv : Ws) + l * 4096;
    u16 b[8];
    #pragma unroll
    for (int j = 0; j < 8; ++j) b[j] = f2bf(W[(kc * 8 + j) * 64 + col]);
    uint4 pk;
    pk.x = (u32)b[0] | ((u32)b[1] << 16);
    pk.y = (u32)b[2] | ((u32)b[3] << 16);
    pk.z = (u32)b[4] | ((u32)b[5] << 16);
    pk.w = (u32)b[6] | ((u32)b[7] << 16);
    *(uint4*)(Wtb + ((size_t)(l * 256 + m * 64 + col)) * 64 + kc * 8) = pk;
}

// ---------------- fused MFMA GEMM: q (f32), k|v (bf16), h@Ws+bs (f32) ----------------
__global__ __launch_bounds__(256) void gemm_mfma(
    const u16* __restrict__ hb, const u16* __restrict__ Wtb,
    const float* __restrict__ bq, const float* __restrict__ bk,
    const float* __restrict__ bv, const float* __restrict__ bs,
    float* __restrict__ q, u16* __restrict__ kv, float* __restrict__ hnext) {
    __shared__ u16 Alds[64 * 72];    //  9216 B
    __shared__ u16 Blds[256 * 72];   // 36864 B
    int t = threadIdx.x;
    int wave = t >> 6, lane = t & 63;
    int nb = blockIdx.x * 64;

    #pragma unroll
    for (int i = 0; i < 2; ++i) {
        int c = t + 256 * i;
        int row = c >> 3, k8 = c & 7;
        int node = nb + row;
        if (node >= N_NODES) node = 0;
        *(uint4*)(Alds + row * 72 + k8 * 8) =
            *(const uint4*)(hb + (size_t)node * 64 + k8 * 8);
    }
    #pragma unroll
    for (int i = 0; i < 8; ++i) {
        int c = t + 256 * i;
        int col = c >> 3, k8 = c & 7;
        *(uint4*)(Blds + col * 72 + k8 * 8) =
            *(const uint4*)(Wtb + (size_t)col * 64 + k8 * 8);
    }
    __syncthreads();

    int lr = lane & 15, lg4 = lane >> 4;
    const float* bm = (wave == 0) ? bq : (wave == 1) ? bk : (wave == 2) ? bv : bs;

    f32x4 acc[4][4];
    #pragma unroll
    for (int ct = 0; ct < 4; ++ct) {
        float bval = bm[ct * 16 + lr];
        #pragma unroll
        for (int rt = 0; rt < 4; ++rt) acc[rt][ct] = (f32x4){bval, bval, bval, bval};
    }

    #pragma unroll
    for (int s = 0; s < 2; ++s) {
        bf16x8 af[4], bfr[4];
        #pragma unroll
        for (int rt = 0; rt < 4; ++rt)
            af[rt] = *(const bf16x8*)(Alds + (rt * 16 + lr) * 72 + s * 32 + lg4 * 8);
        #pragma unroll
        for (int ct = 0; ct < 4; ++ct)
            bfr[ct] = *(const bf16x8*)(Blds + (wave * 64 + ct * 16 + lr) * 72 + s * 32 + lg4 * 8);
        #pragma unroll
        for (int rt = 0; rt < 4; ++rt)
            #pragma unroll
            for (int ct = 0; ct < 4; ++ct)
                acc[rt][ct] = __builtin_amdgcn_mfma_f32_16x16x32_bf16(
                    af[rt], bfr[ct], acc[rt][ct], 0, 0, 0);
    }

    #pragma unroll
    for (int rt = 0; rt < 4; ++rt) {
        #pragma unroll
        for (int r = 0; r < 4; ++r) {
            int row = rt * 16 + lg4 * 4 + r;
            int node = nb + row;
            if (node >= N_NODES) continue;
            if (wave == 0) {
                #pragma unroll
                for (int ct = 0; ct < 4; ++ct)
                    q[(size_t)node * 64 + ct * 16 + lr] = acc[rt][ct][r];
            } else if (wave == 1) {
                #pragma unroll
                for (int ct = 0; ct < 4; ++ct)
                    kv[(size_t)node * 128 + ct * 16 + lr] = f2bf(acc[rt][ct][r]);
            } else if (wave == 2) {
                #pragma unroll
                for (int ct = 0; ct < 4; ++ct)
                    kv[(size_t)node * 128 + 64 + ct * 16 + lr] = f2bf(acc[rt][ct][r]);
            } else {
                #pragma unroll
                for (int ct = 0; ct < 4; ++ct)
                    hnext[(size_t)node * 64 + ct * 16 + lr] = acc[rt][ct][r];
            }
        }
    }
}

// ---------------- edge attention ----------------
__global__ __launch_bounds__(256) void edge_attn(
    const float* __restrict__ q, const u16* __restrict__ kv,
    const int* __restrict__ offs, const int* __restrict__ csr_src,
    float* __restrict__ hnext, u16* __restrict__ hb) {
    int wave = threadIdx.x >> 6, lane = threadIdx.x & 63;
    int n = blockIdx.x * 4 + wave;
    int g = lane >> 3, lg = lane & 7;
    const float* qp = q + (size_t)n * 64 + lg * 8;
    float4 q0 = *(const float4*)qp;
    float4 q1 = *(const float4*)(qp + 4);
    int e0 = offs[n], e1 = offs[n + 1];
    float m = -3.0e38f, z = 0.f;
    float a8[8] = {0.f, 0.f, 0.f, 0.f, 0.f, 0.f, 0.f, 0.f};
    for (int e = e0 + g; e < e1; e += 8) {
        int sg = csr_src[e];
        const u16* kvp = kv + (size_t)sg * 128 + lg * 8;
        uint4 ku = *(const uint4*)kvp;
        uint4 vu = *(const uint4*)(kvp + 64);
        float d;
        d = bf_lo(ku.x) * q0.x;
        d = fmaf(bf_hi(ku.x), q0.y, d);
        d = fmaf(bf_lo(ku.y), q0.z, d);
        d = fmaf(bf_hi(ku.y), q0.w, d);
        d = fmaf(bf_lo(ku.z), q1.x, d);
        d = fmaf(bf_hi(ku.z), q1.y, d);
        d = fmaf(bf_lo(ku.w), q1.z, d);
        d = fmaf(bf_hi(ku.w), q1.w, d);
        d += __shfl_xor(d, 1);
        d += __shfl_xor(d, 2);
        d += __shfl_xor(d, 4);
        float alpha = d * 0.125f;             // 1/sqrt(64)
        float mn = fmaxf(m, alpha);
        float c = __expf(m - mn);
        float p = __expf(alpha - mn);
        z = z * c + p;
        a8[0] = a8[0] * c + p * bf_lo(vu.x);
        a8[1] = a8[1] * c + p * bf_hi(vu.x);
        a8[2] = a8[2] * c + p * bf_lo(vu.y);
        a8[3] = a8[3] * c + p * bf_hi(vu.y);
        a8[4] = a8[4] * c + p * bf_lo(vu.z);
        a8[5] = a8[5] * c + p * bf_hi(vu.z);
        a8[6] = a8[6] * c + p * bf_lo(vu.w);
        a8[7] = a8[7] * c + p * bf_hi(vu.w);
        m = mn;
    }
    float M = m;
    M = fmaxf(M, __shfl_xor(M, 8));
    M = fmaxf(M, __shfl_xor(M, 16));
    M = fmaxf(M, __shfl_xor(M, 32));
    float s = __expf(m - M);
    z *= s;
    z += __shfl_xor(z, 8); z += __shfl_xor(z, 16); z += __shfl_xor(z, 32);
    #pragma unroll
    for (int j = 0; j < 8; ++j) {
        float a = a8[j] * s;
        a += __shfl_xor(a, 8); a += __shfl_xor(a, 16); a += __shfl_xor(a, 32);
        a8[j] = a;
    }
    if (g == 0) {
        float invz = 1.f / (z + 1e-16f);
        float* hp = hnext + (size_t)n * 64 + lg * 8;
        float4 h0 = *(const float4*)hp;
        float4 h1 = *(const float4*)(hp + 4);
        float r0 = h0.x + a8[0] * invz;
        float r1 = h0.y + a8[1] * invz;
        float r2 = h0.z + a8[2] * invz;
        float r3 = h0.w + a8[3] * invz;
        float r4 = h1.x + a8[4] * invz;
        float r5 = h1.y + a8[5] * invz;
        float r6 = h1.z + a8[6] * invz;
        float r7 = h1.w + a8[7] * invz;
        *(float4*)hp = make_float4(r0, r1, r2, r3);
        *(float4*)(hp + 4) = make_float4(r4, r5, r6, r7);
        uint4 pk;
        pk.x = (u32)f2bf(r0) | ((u32)f2bf(r1) << 16);
        pk.y = (u32)f2bf(r2) | ((u32)f2bf(r3) << 16);
        pk.z = (u32)f2bf(r4) | ((u32)f2bf(r5) << 16);
        pk.w = (u32)f2bf(r6) | ((u32)f2bf(r7) << 16);
        *(uint4*)(hb + (size_t)n * 64 + lg * 8) = pk;
    }
}

// ---------------- pooling: parallel partial sums + tiny finalize ----------------
// pool_sums: 256 blocks, block b owns nodes [b*196, min((b+1)*196, N)).
// thread t: dim d = t&63, sub-sequence sub = t>>6 (stride 4 over nodes).
// Running acc flushed to gsums[g*64+d] at graph boundaries (batch sorted).
__global__ __launch_bounds__(256) void pool_sums(const float* __restrict__ h,
                                                 const int* __restrict__ batch,
                                                 float* __restrict__ gsums) {
    int b = blockIdx.x, t = threadIdx.x;
    int d = t & 63, sub = t >> 6;
    int lo = b * POOL_CHUNK;
    int hi = lo + POOL_CHUNK;
    if (hi > N_NODES) hi = N_NODES;
    float acc = 0.f;
    int curg = -1;
    for (int n = lo + sub; n < hi; n += 4) {
        int g = batch[n];
        if (g != curg) {
            if (curg >= 0) atomicAdd(&gsums[curg * 64 + d], acc);
            acc = 0.f;
            curg = g;
        }
        acc += h[(size_t)n * 64 + d];
    }
    if (curg >= 0) atomicAdd(&gsums[curg * 64 + d], acc);
}

__device__ __forceinline__ int lbound(const int* a, int n, int key) {
    int lo = 0, hi = n;
    while (lo < hi) {
        int mid = (lo + hi) >> 1;
        if (a[mid] < key) lo = mid + 1; else hi = mid;
    }
    return lo;
}

// finalize: 1 block, 256 threads. counts via binary search; out = (sums/cnt)@Wf + bf
__global__ __launch_bounds__(256) void finalize(const float* __restrict__ gsums,
                                                const int* __restrict__ batch,
                                                const float* __restrict__ Wf,
                                                const float* __restrict__ bf,
                                                float* __restrict__ out) {
    __shared__ float pl[N_GRAPHS][DIM];
    __shared__ int bnd[N_GRAPHS + 1];
    int t = threadIdx.x;
    if (t <= N_GRAPHS) bnd[t] = (t == N_GRAPHS) ? N_NODES : lbound(batch, N_NODES, t);
    __syncthreads();
    // normalize sums -> means
    for (int i = t; i < N_GRAPHS * DIM; i += 256) {
        int g = i >> 6;
        int cnt = bnd[g + 1] - bnd[g];
        pl[g][i & 63] = gsums[i] / (float)(cnt > 1 ? cnt : 1);
    }
    __syncthreads();
    // out[g][o] ; 640 outputs
    for (int i = t; i < N_GRAPHS * OUT_DIM; i += 256) {
        int g = i / OUT_DIM, o = i % OUT_DIM;
        float acc = bf[o];
        #pragma unroll
        for (int d = 0; d < DIM; ++d) acc = fmaf(pl[g][d], Wf[d * OUT_DIM + o], acc);
        out[i] = acc;
    }
}

// ---------------- launch ----------------
extern "C" void kernel_launch(void* const* d_in, const int* in_sizes, int n_in,
                              void* d_out, int out_size, void* d_ws, size_t ws_size,
                              hipStream_t stream) {
    const float* x    = (const float*)d_in[0];
    const int*   ei   = (const int*)d_in[1];
    const int*   batch= (const int*)d_in[2];
    const float* Wq   = (const float*)d_in[3];
    const float* bq   = (const float*)d_in[4];
    const float* Wk   = (const float*)d_in[5];
    const float* bk   = (const float*)d_in[6];
    const float* Wv   = (const float*)d_in[7];
    const float* bv   = (const float*)d_in[8];
    const float* Ws   = (const float*)d_in[9];
    const float* bs   = (const float*)d_in[10];
    const float* Wf   = (const float*)d_in[11];
    const float* bf   = (const float*)d_in[12];
    float* out = (float*)d_out;

    char* ws = (char*)d_ws;
    float* qb   = (float*)(ws + 0);            // 12.8 MB
    float* hA   = (float*)(ws + 12800000);     // 12.8 MB
    float* hB   = (float*)(ws + 25600000);     // 12.8 MB
    u16*   kvb  = (u16*)  (ws + 38400000);     // 12.8 MB (bf16)
    u16*   hb   = (u16*)  (ws + 51200000);     //  6.4 MB (bf16)
    u16*   Wtb  = (u16*)  (ws + 57600000);     //  256 KB
    int*   csr  = (int*)  (ws + 57862144);     //  3.2 MB
    int*   offs = (int*)  (ws + 61062144);     //  200 KB
    int*   cur  = (int*)  (ws + 61262848);     //  200 KB
    int*   bsums= (int*)  (ws + 61463552);     //  4 KB
    float* gsums= (float*)(ws + 61467648);     //  16 KB (64*64 f32)

    const int* srcI = ei;
    const int* dstI = ei + N_EDGES;

    // clear cur + gsums regions
    hipMemsetAsync(cur, 0, N_NODES * sizeof(int), stream);
    hipMemsetAsync(gsums, 0, N_GRAPHS * DIM * sizeof(float), stream);

    count_kernel<<<N_EDGES / 256, 256, 0, stream>>>(dstI, cur);
    scan1<<<NBLK_N, 256, 0, stream>>>(cur, offs, bsums);
    scan2<<<1, 256, 0, stream>>>(bsums, NBLK_N);
    scan3<<<NBLK_N, 256, 0, stream>>>(offs, bsums);
    hipMemsetAsync(cur, 0, N_NODES * sizeof(int), stream);
    scatter_kernel<<<N_EDGES / 256, 256, 0, stream>>>(srcI, dstI, offs, cur, csr);

    convert_x<<<(N_NODES * 8 + 255) / 256, 256, 0, stream>>>(x, hb);
    transpose_w<<<32, 256, 0, stream>>>(Wq, Wk, Wv, Ws, Wtb);

    float* hout = hA;
    const float* hin = nullptr;
    for (int l = 0; l < 4; ++l) {
        gemm_mfma<<<(N_NODES + 63) / 64, 256, 0, stream>>>(
            hb, Wtb + (size_t)l * 16384,
            bq + l * 64, bk + l * 64, bv + l * 64, bs + l * 64,
            qb, kvb, hout);
        edge_attn<<<N_NODES / 4, 256, 0, stream>>>(qb, kvb, offs, csr, hout, hb);
        hin = hout;
        hout = (hout == hA) ? hB : hA;
    }
    pool_sums<<<POOL_BLOCKS, 256, 0, stream>>>(hin, batch, gsums);
    finalize<<<1, 256, 0, stream>>>(gsums, batch, Wf, bf, out);
}

// Round 5
// 279.365 us; speedup vs baseline: 34.5772x; 1.2000x over previous
//
#include <hip/hip_runtime.h>
#include <hip/hip_bf16.h>

typedef unsigned short u16;
typedef unsigned int   u32;
typedef short bf16x8 __attribute__((ext_vector_type(8)));
typedef float f32x4  __attribute__((ext_vector_type(4)));

#define N_NODES  50000
#define N_EDGES  800000
#define DIM      64
#define N_GRAPHS 64
#define OUT_DIM  10
#define POOL_BLOCKS 256
#define POOL_CHUNK  ((N_NODES + POOL_BLOCKS - 1) / POOL_BLOCKS)   // 196

// bucket CSR build
#define BSHIFT 8
#define NBUCK  196          // ceil(50000/256)
#define BCAP   5000         // mean 4096, sd ~64 -> statically safe
#define EPB    2048         // edges per block in bucket_scatter
#define NBLK_A ((N_EDGES + EPB - 1) / EPB)   // 391

__device__ __forceinline__ u16 f2bf(float f) {
    u32 u = __float_as_uint(f);
    u32 r = (u + 0x7fffu + ((u >> 16) & 1u)) >> 16;
    return (u16)r;
}
__device__ __forceinline__ float bf_lo(u32 u) { return __uint_as_float(u << 16); }
__device__ __forceinline__ float bf_hi(u32 u) { return __uint_as_float(u & 0xffff0000u); }

// ---------------- bucketed CSR build ----------------
// A: bin edges into 196 dst-range buckets; contiguous reserved runs -> ~1x write amp.
__global__ __launch_bounds__(256) void bucket_scatter(const int* __restrict__ src,
                                                      const int* __restrict__ dst,
                                                      int* __restrict__ bcur,
                                                      u32* __restrict__ bscratch) {
    __shared__ int hist[NBUCK];
    __shared__ int base[NBUCK];
    int t = threadIdx.x;
    for (int i = t; i < NBUCK; i += 256) hist[i] = 0;
    __syncthreads();
    int e0 = blockIdx.x * EPB;
    u32 packed[8];
    int bb[8];
    #pragma unroll
    for (int i = 0; i < 8; ++i) {
        int e = e0 + i * 256 + t;
        if (e < N_EDGES) {
            int d = dst[e], s = src[e];
            bb[i] = d >> BSHIFT;
            packed[i] = ((u32)s << BSHIFT) | (u32)(d & ((1 << BSHIFT) - 1));
            atomicAdd(&hist[bb[i]], 1);
        } else bb[i] = -1;
    }
    __syncthreads();
    for (int i = t; i < NBUCK; i += 256)
        base[i] = (hist[i] > 0) ? atomicAdd(&bcur[i], hist[i]) : 0;
    __syncthreads();
    #pragma unroll
    for (int i = 0; i < 8; ++i) {
        if (bb[i] >= 0) {
            int pos = atomicAdd(&base[bb[i]], 1);
            bscratch[bb[i] * BCAP + pos] = packed[i];
        }
    }
}

// B: exclusive scan of bucket totals
__global__ void scan_buckets(const int* __restrict__ bcur, int* __restrict__ bbase) {
    __shared__ int s[256];
    int t = threadIdx.x;
    int v = (t < NBUCK) ? bcur[t] : 0;
    s[t] = v;
    __syncthreads();
    for (int d = 1; d < 256; d <<= 1) {
        int tmp = (t >= d) ? s[t - d] : 0;
        __syncthreads();
        s[t] += tmp;
        __syncthreads();
    }
    if (t < NBUCK) bbase[t] = s[t] - v;
}

// C: per-bucket count/scan/scatter fully in LDS; dense offs + csr writes.
__global__ __launch_bounds__(256) void csr_build(const u32* __restrict__ bscratch,
                                                 const int* __restrict__ bcur,
                                                 const int* __restrict__ bbase,
                                                 int* __restrict__ offs,
                                                 int* __restrict__ csr) {
    __shared__ int cnt[256];
    __shared__ int sc[256];
    __shared__ int cur2[256];
    int b = blockIdx.x, t = threadIdx.x;
    cnt[t] = 0;
    __syncthreads();
    int n_b = bcur[b];
    int gbase = bbase[b];
    const u32* bp = bscratch + (size_t)b * BCAP;
    for (int i = t; i < n_b; i += 256) atomicAdd(&cnt[bp[i] & 255], 1);
    __syncthreads();
    int v = cnt[t];
    sc[t] = v;
    __syncthreads();
    for (int d = 1; d < 256; d <<= 1) {
        int tmp = (t >= d) ? sc[t - d] : 0;
        __syncthreads();
        sc[t] += tmp;
        __syncthreads();
    }
    int excl = sc[t] - v;
    int node = (b << BSHIFT) + t;
    if (node < N_NODES) offs[node] = gbase + excl;
    if (b == NBUCK - 1 && t == 0) offs[N_NODES] = N_EDGES;
    cur2[t] = gbase + excl;
    __syncthreads();
    for (int i = t; i < n_b; i += 256) {
        u32 p = bp[i];
        int pos = atomicAdd(&cur2[p & 255], 1);
        csr[pos] = (int)(p >> BSHIFT);
    }
}

// ---------------- precompute: x -> bf16, W -> bf16 transposed ----------------

__global__ __launch_bounds__(256) void convert_x(const float* __restrict__ x,
                                                 u16* __restrict__ hb) {
    int c = blockIdx.x * 256 + threadIdx.x;      // chunk of 8 elems
    if (c >= N_NODES * 8) return;
    const float* src = x + (size_t)c * 8;
    float4 f0 = *(const float4*)src;
    float4 f1 = *(const float4*)(src + 4);
    uint4 pk;
    pk.x = (u32)f2bf(f0.x) | ((u32)f2bf(f0.y) << 16);
    pk.y = (u32)f2bf(f0.z) | ((u32)f2bf(f0.w) << 16);
    pk.z = (u32)f2bf(f1.x) | ((u32)f2bf(f1.y) << 16);
    pk.w = (u32)f2bf(f1.z) | ((u32)f2bf(f1.w) << 16);
    *(uint4*)(hb + (size_t)c * 8) = pk;
}

// Wtb[l][m*64+col][k]  (bf16), from W[l][k][col] fp32
__global__ __launch_bounds__(256) void transpose_w(
    const float* __restrict__ Wq, const float* __restrict__ Wk,
    const float* __restrict__ Wv, const float* __restrict__ Ws,
    u16* __restrict__ Wtb) {
    int id = blockIdx.x * 256 + threadIdx.x;     // 8192 total
    if (id >= 8192) return;
    int kc  = id & 7;
    int col = (id >> 3) & 63;
    int m   = (id >> 9) & 3;
    int l   = id >> 11;
    const float* W = ((m == 0) ? Wq : (m == 1) ? Wk : (m == 2) ? Wv : Ws) + l * 4096;
    u16 b[8];
    #pragma unroll
    for (int j = 0; j < 8; ++j) b[j] = f2bf(W[(kc * 8 + j) * 64 + col]);
    uint4 pk;
    pk.x = (u32)b[0] | ((u32)b[1] << 16);
    pk.y = (u32)b[2] | ((u32)b[3] << 16);
    pk.z = (u32)b[4] | ((u32)b[5] << 16);
    pk.w = (u32)b[6] | ((u32)b[7] << 16);
    *(uint4*)(Wtb + ((size_t)(l * 256 + m * 64 + col)) * 64 + kc * 8) = pk;
}

// ---------------- fused MFMA GEMM: q (bf16), k|v (bf16), h@Ws+bs (f32) ----------------
__global__ __launch_bounds__(256) void gemm_mfma(
    const u16* __restrict__ hb, const u16* __restrict__ Wtb,
    const float* __restrict__ bq, const float* __restrict__ bk,
    const float* __restrict__ bv, const float* __restrict__ bs,
    u16* __restrict__ q, u16* __restrict__ kv, float* __restrict__ hnext) {
    __shared__ u16 Alds[64 * 72];    //  9216 B
    __shared__ u16 Blds[256 * 72];   // 36864 B
    int t = threadIdx.x;
    int wave = t >> 6, lane = t & 63;
    int nb = blockIdx.x * 64;

    #pragma unroll
    for (int i = 0; i < 2; ++i) {
        int c = t + 256 * i;
        int row = c >> 3, k8 = c & 7;
        int node = nb + row;
        if (node >= N_NODES) node = 0;
        *(uint4*)(Alds + row * 72 + k8 * 8) =
            *(const uint4*)(hb + (size_t)node * 64 + k8 * 8);
    }
    #pragma unroll
    for (int i = 0; i < 8; ++i) {
        int c = t + 256 * i;
        int col = c >> 3, k8 = c & 7;
        *(uint4*)(Blds + col * 72 + k8 * 8) =
            *(const uint4*)(Wtb + (size_t)col * 64 + k8 * 8);
    }
    __syncthreads();

    int lr = lane & 15, lg4 = lane >> 4;
    const float* bm = (wave == 0) ? bq : (wave == 1) ? bk : (wave == 2) ? bv : bs;

    f32x4 acc[4][4];
    #pragma unroll
    for (int ct = 0; ct < 4; ++ct) {
        float bval = bm[ct * 16 + lr];
        #pragma unroll
        for (int rt = 0; rt < 4; ++rt) acc[rt][ct] = (f32x4){bval, bval, bval, bval};
    }

    #pragma unroll
    for (int s = 0; s < 2; ++s) {
        bf16x8 af[4], bfr[4];
        #pragma unroll
        for (int rt = 0; rt < 4; ++rt)
            af[rt] = *(const bf16x8*)(Alds + (rt * 16 + lr) * 72 + s * 32 + lg4 * 8);
        #pragma unroll
        for (int ct = 0; ct < 4; ++ct)
            bfr[ct] = *(const bf16x8*)(Blds + (wave * 64 + ct * 16 + lr) * 72 + s * 32 + lg4 * 8);
        #pragma unroll
        for (int rt = 0; rt < 4; ++rt)
            #pragma unroll
            for (int ct = 0; ct < 4; ++ct)
                acc[rt][ct] = __builtin_amdgcn_mfma_f32_16x16x32_bf16(
                    af[rt], bfr[ct], acc[rt][ct], 0, 0, 0);
    }

    #pragma unroll
    for (int rt = 0; rt < 4; ++rt) {
        #pragma unroll
        for (int r = 0; r < 4; ++r) {
            int row = rt * 16 + lg4 * 4 + r;
            int node = nb + row;
            if (node >= N_NODES) continue;
            if (wave == 0) {
                #pragma unroll
                for (int ct = 0; ct < 4; ++ct)
                    q[(size_t)node * 64 + ct * 16 + lr] = f2bf(acc[rt][ct][r]);
            } else if (wave == 1) {
                #pragma unroll
                for (int ct = 0; ct < 4; ++ct)
                    kv[(size_t)node * 128 + ct * 16 + lr] = f2bf(acc[rt][ct][r]);
            } else if (wave == 2) {
                #pragma unroll
                for (int ct = 0; ct < 4; ++ct)
                    kv[(size_t)node * 128 + 64 + ct * 16 + lr] = f2bf(acc[rt][ct][r]);
            } else {
                #pragma unroll
                for (int ct = 0; ct < 4; ++ct)
                    hnext[(size_t)node * 64 + ct * 16 + lr] = acc[rt][ct][r];
            }
        }
    }
}

// ---------------- edge attention ----------------
__global__ __launch_bounds__(256) void edge_attn(
    const u16* __restrict__ q, const u16* __restrict__ kv,
    const int* __restrict__ offs, const int* __restrict__ csr_src,
    float* __restrict__ hnext, u16* __restrict__ hb) {
    int wave = threadIdx.x >> 6, lane = threadIdx.x & 63;
    int n = blockIdx.x * 4 + wave;
    int g = lane >> 3, lg = lane & 7;
    uint4 qu = *(const uint4*)(q + (size_t)n * 64 + lg * 8);
    float q0 = bf_lo(qu.x), q1 = bf_hi(qu.x);
    float q2 = bf_lo(qu.y), q3 = bf_hi(qu.y);
    float q4 = bf_lo(qu.z), q5 = bf_hi(qu.z);
    float q6 = bf_lo(qu.w), q7 = bf_hi(qu.w);
    int e0 = offs[n], e1 = offs[n + 1];
    float m = -3.0e38f, z = 0.f;
    float a8[8] = {0.f, 0.f, 0.f, 0.f, 0.f, 0.f, 0.f, 0.f};
    for (int e = e0 + g; e < e1; e += 8) {
        int sg = csr_src[e];
        const u16* kvp = kv + (size_t)sg * 128 + lg * 8;
        uint4 ku = *(const uint4*)kvp;
        uint4 vu = *(const uint4*)(kvp + 64);
        float d;
        d = bf_lo(ku.x) * q0;
        d = fmaf(bf_hi(ku.x), q1, d);
        d = fmaf(bf_lo(ku.y), q2, d);
        d = fmaf(bf_hi(ku.y), q3, d);
        d = fmaf(bf_lo(ku.z), q4, d);
        d = fmaf(bf_hi(ku.z), q5, d);
        d = fmaf(bf_lo(ku.w), q6, d);
        d = fmaf(bf_hi(ku.w), q7, d);
        d += __shfl_xor(d, 1);
        d += __shfl_xor(d, 2);
        d += __shfl_xor(d, 4);
        float alpha = d * 0.125f;             // 1/sqrt(64)
        float mn = fmaxf(m, alpha);
        float c = __expf(m - mn);
        float p = __expf(alpha - mn);
        z = z * c + p;
        a8[0] = a8[0] * c + p * bf_lo(vu.x);
        a8[1] = a8[1] * c + p * bf_hi(vu.x);
        a8[2] = a8[2] * c + p * bf_lo(vu.y);
        a8[3] = a8[3] * c + p * bf_hi(vu.y);
        a8[4] = a8[4] * c + p * bf_lo(vu.z);
        a8[5] = a8[5] * c + p * bf_hi(vu.z);
        a8[6] = a8[6] * c + p * bf_lo(vu.w);
        a8[7] = a8[7] * c + p * bf_hi(vu.w);
        m = mn;
    }
    float M = m;
    M = fmaxf(M, __shfl_xor(M, 8));
    M = fmaxf(M, __shfl_xor(M, 16));
    M = fmaxf(M, __shfl_xor(M, 32));
    float s = __expf(m - M);
    z *= s;
    z += __shfl_xor(z, 8); z += __shfl_xor(z, 16); z += __shfl_xor(z, 32);
    #pragma unroll
    for (int j = 0; j < 8; ++j) {
        float a = a8[j] * s;
        a += __shfl_xor(a, 8); a += __shfl_xor(a, 16); a += __shfl_xor(a, 32);
        a8[j] = a;
    }
    if (g == 0) {
        float invz = 1.f / (z + 1e-16f);
        float* hp = hnext + (size_t)n * 64 + lg * 8;
        float4 h0 = *(const float4*)hp;
        float4 h1 = *(const float4*)(hp + 4);
        float r0 = h0.x + a8[0] * invz;
        float r1 = h0.y + a8[1] * invz;
        float r2 = h0.z + a8[2] * invz;
        float r3 = h0.w + a8[3] * invz;
        float r4 = h1.x + a8[4] * invz;
        float r5 = h1.y + a8[5] * invz;
        float r6 = h1.z + a8[6] * invz;
        float r7 = h1.w + a8[7] * invz;
        *(float4*)hp = make_float4(r0, r1, r2, r3);
        *(float4*)(hp + 4) = make_float4(r4, r5, r6, r7);
        uint4 pk;
        pk.x = (u32)f2bf(r0) | ((u32)f2bf(r1) << 16);
        pk.y = (u32)f2bf(r2) | ((u32)f2bf(r3) << 16);
        pk.z = (u32)f2bf(r4) | ((u32)f2bf(r5) << 16);
        pk.w = (u32)f2bf(r6) | ((u32)f2bf(r7) << 16);
        *(uint4*)(hb + (size_t)n * 64 + lg * 8) = pk;
    }
}

// ---------------- pooling: parallel partial sums + tiny finalize ----------------
__global__ __launch_bounds__(256) void pool_sums(const float* __restrict__ h,
                                                 const int* __restrict__ batch,
                                                 float* __restrict__ gsums) {
    int b = blockIdx.x, t = threadIdx.x;
    int d = t & 63, sub = t >> 6;
    int lo = b * POOL_CHUNK;
    int hi = lo + POOL_CHUNK;
    if (hi > N_NODES) hi = N_NODES;
    float acc = 0.f;
    int curg = -1;
    for (int n = lo + sub; n < hi; n += 4) {
        int g = batch[n];
        if (g != curg) {
            if (curg >= 0) atomicAdd(&gsums[curg * 64 + d], acc);
            acc = 0.f;
            curg = g;
        }
        acc += h[(size_t)n * 64 + d];
    }
    if (curg >= 0) atomicAdd(&gsums[curg * 64 + d], acc);
}

__device__ __forceinline__ int lbound(const int* a, int n, int key) {
    int lo = 0, hi = n;
    while (lo < hi) {
        int mid = (lo + hi) >> 1;
        if (a[mid] < key) lo = mid + 1; else hi = mid;
    }
    return lo;
}

__global__ __launch_bounds__(256) void finalize(const float* __restrict__ gsums,
                                                const int* __restrict__ batch,
                                                const float* __restrict__ Wf,
                                                const float* __restrict__ bf,
                                                float* __restrict__ out) {
    __shared__ float pl[N_GRAPHS][DIM];
    __shared__ int bnd[N_GRAPHS + 1];
    int t = threadIdx.x;
    if (t <= N_GRAPHS) bnd[t] = (t == N_GRAPHS) ? N_NODES : lbound(batch, N_NODES, t);
    __syncthreads();
    for (int i = t; i < N_GRAPHS * DIM; i += 256) {
        int g = i >> 6;
        int cnt = bnd[g + 1] - bnd[g];
        pl[g][i & 63] = gsums[i] / (float)(cnt > 1 ? cnt : 1);
    }
    __syncthreads();
    for (int i = t; i < N_GRAPHS * OUT_DIM; i += 256) {
        int g = i / OUT_DIM, o = i % OUT_DIM;
        float acc = bf[o];
        #pragma unroll
        for (int d = 0; d < DIM; ++d) acc = fmaf(pl[g][d], Wf[d * OUT_DIM + o], acc);
        out[i] = acc;
    }
}

// ---------------- launch ----------------
extern "C" void kernel_launch(void* const* d_in, const int* in_sizes, int n_in,
                              void* d_out, int out_size, void* d_ws, size_t ws_size,
                              hipStream_t stream) {
    const float* x    = (const float*)d_in[0];
    const int*   ei   = (const int*)d_in[1];
    const int*   batch= (const int*)d_in[2];
    const float* Wq   = (const float*)d_in[3];
    const float* bq   = (const float*)d_in[4];
    const float* Wk   = (const float*)d_in[5];
    const float* bk   = (const float*)d_in[6];
    const float* Wv   = (const float*)d_in[7];
    const float* bv   = (const float*)d_in[8];
    const float* Ws   = (const float*)d_in[9];
    const float* bs   = (const float*)d_in[10];
    const float* Wf   = (const float*)d_in[11];
    const float* bf   = (const float*)d_in[12];
    float* out = (float*)d_out;

    char* ws = (char*)d_ws;
    u16*   qb16 = (u16*)  (ws + 0);            //  6.4 MB
    float* hA   = (float*)(ws + 6400000);      // 12.8 MB
    float* hB   = (float*)(ws + 19200000);     // 12.8 MB
    u16*   kvb  = (u16*)  (ws + 32000000);     // 12.8 MB (bf16)
    u16*   hb   = (u16*)  (ws + 44800000);     //  6.4 MB (bf16)
    u16*   Wtb  = (u16*)  (ws + 51200000);     //  256 KB
    int*   csr  = (int*)  (ws + 51462144);     //  3.2 MB
    int*   offs = (int*)  (ws + 54662144);     //  200 KB + 4
    u32*   bscr = (u32*)  (ws + 54863104);     //  3.92 MB (196*5000*4)
    int*   bcur = (int*)  (ws + 58783104);     //  784 B
    int*   bbase= (int*)  (ws + 58784128);     //  784 B
    float* gsums= (float*)(ws + 58785792);     //  16 KB

    const int* srcI = ei;
    const int* dstI = ei + N_EDGES;

    hipMemsetAsync(bcur, 0, NBUCK * sizeof(int), stream);
    hipMemsetAsync(gsums, 0, N_GRAPHS * DIM * sizeof(float), stream);

    bucket_scatter<<<NBLK_A, 256, 0, stream>>>(srcI, dstI, bcur, bscr);
    scan_buckets<<<1, 256, 0, stream>>>(bcur, bbase);
    csr_build<<<NBUCK, 256, 0, stream>>>(bscr, bcur, bbase, offs, csr);

    convert_x<<<(N_NODES * 8 + 255) / 256, 256, 0, stream>>>(x, hb);
    transpose_w<<<32, 256, 0, stream>>>(Wq, Wk, Wv, Ws, Wtb);

    float* hout = hA;
    const float* hin = nullptr;
    for (int l = 0; l < 4; ++l) {
        gemm_mfma<<<(N_NODES + 63) / 64, 256, 0, stream>>>(
            hb, Wtb + (size_t)l * 16384,
            bq + l * 64, bk + l * 64, bv + l * 64, bs + l * 64,
            qb16, kvb, hout);
        edge_attn<<<N_NODES / 4, 256, 0, stream>>>(qb16, kvb, offs, csr, hout, hb);
        hin = hout;
        hout = (hout == hA) ? hB : hA;
    }
    pool_sums<<<POOL_BLOCKS, 256, 0, stream>>>(hin, batch, gsums);
    finalize<<<1, 256, 0, stream>>>(gsums, batch, Wf, bf, out);
}